// Round 10
// baseline (284.185 us; speedup 1.0000x reference)
//
#include <hip/hip_runtime.h>

#define DEVINL __device__ __forceinline__

typedef __attribute__((ext_vector_type(8))) short bf16x8;
typedef __attribute__((ext_vector_type(4))) float f32x4;
typedef _Float16 half2_t __attribute__((ext_vector_type(2)));
typedef _Float16 f16x8 __attribute__((ext_vector_type(8)));

DEVINL unsigned short f2bf(float f) {
  unsigned int u = __float_as_uint(f);
  u += 0x7FFFu + ((u >> 16) & 1u);
  return (unsigned short)(u >> 16);
}
DEVINL float sigmf(float x) { return 1.f / (1.f + __expf(-x)); }
DEVINL float tanh_fast(float x) { float e = __expf(2.f * x); return 1.f - 2.f / (e + 1.f); }

DEVINL float fdot2u(unsigned int h, unsigned int w, float acc) {
  return __builtin_amdgcn_fdot2(__builtin_bit_cast(half2_t, h),
                                __builtin_bit_cast(half2_t, w), acc, false);
}

// ---------------- conversion / pack helpers ----------------

__global__ __launch_bounds__(256) void conv_bf16(const float* __restrict__ in,
                                                 unsigned short* __restrict__ out) {
  int id = blockIdx.x * 256 + threadIdx.x;   // 4,096,000 exact
  float4 v = *(const float4*)&in[(size_t)id * 4];
  unsigned int a = (unsigned int)f2bf(v.x) | ((unsigned int)f2bf(v.y) << 16);
  unsigned int b = (unsigned int)f2bf(v.z) | ((unsigned int)f2bf(v.w) << 16);
  *(uint2*)&out[(size_t)id * 4] = make_uint2(a, b);
}

// elementwise f32 -> f16 (Wih1 [1024][256] stays row-major)
__global__ __launch_bounds__(256) void conv_f16(const float* __restrict__ in,
                                                unsigned short* __restrict__ out) {
  int id = blockIdx.x * 256 + threadIdx.x;   // 262,144 exact
  out[id] = __builtin_bit_cast(unsigned short, (_Float16)in[id]);
}

// Whh [1024][256] f32 -> WPK [512 threads][2 cols][128 k-pairs] packed f16
__global__ __launch_bounds__(256) void pack_whh_f16(const float* __restrict__ in,
                                                    unsigned int* __restrict__ out) {
  int id = blockIdx.x * 256 + threadIdx.x;   // 131,072 exact
  int t = id >> 8;
  int cs = (id >> 7) & 1;
  int u = id & 127;
  int col = t + cs * 512;
  float a = in[col * 256 + 2 * u];
  float b = in[col * 256 + 2 * u + 1];
  unsigned short ha = __builtin_bit_cast(unsigned short, (_Float16)a);
  unsigned short hb = __builtin_bit_cast(unsigned short, (_Float16)b);
  out[id] = (unsigned int)ha | ((unsigned int)hb << 16);
}

// ---------------- GCN: separable edge aggregation, fixed-point int LDS atomics ----------------
#define FXSCALE 1048576.f        // 2^20
#define FXINV   (1.f / 1048576.f)

__global__ __launch_bounds__(1024) void gcn_kernel(
    const float* __restrict__ x, const int* __restrict__ ei, const float* __restrict__ ed,
    const float* __restrict__ Wg, const float* __restrict__ bg,
    unsigned short* __restrict__ G) {
  __shared__ float xs[2000];
  __shared__ int Ai[2000];
  __shared__ int Di[2000];
  int bs = blockIdx.x;
  int tid = threadIdx.x;
  for (int i = tid; i < 2000; i += 1024) {
    xs[i] = x[(size_t)bs * 2000 + i];
    Ai[i] = 0; Di[i] = 0;
  }
  __syncthreads();
  const int* srcp = ei + (size_t)bs * 32000;
  const int* dstp = srcp + 16000;
  const float* dp = ed + (size_t)bs * 16000;
  for (int i = tid; i < 4000; i += 1024) {
    int4 s4 = ((const int4*)srcp)[i];
    int4 d4 = ((const int4*)dstp)[i];
    float4 w4 = ((const float4*)dp)[i];
    atomicAdd(&Ai[d4.x], __float2int_rn(w4.x * xs[s4.x] * FXSCALE));
    atomicAdd(&Di[d4.x], __float2int_rn(w4.x * FXSCALE));
    atomicAdd(&Ai[d4.y], __float2int_rn(w4.y * xs[s4.y] * FXSCALE));
    atomicAdd(&Di[d4.y], __float2int_rn(w4.y * FXSCALE));
    atomicAdd(&Ai[d4.z], __float2int_rn(w4.z * xs[s4.z] * FXSCALE));
    atomicAdd(&Di[d4.z], __float2int_rn(w4.z * FXSCALE));
    atomicAdd(&Ai[d4.w], __float2int_rn(w4.w * xs[s4.w] * FXSCALE));
    atomicAdd(&Di[d4.w], __float2int_rn(w4.w * FXSCALE));
  }
  __syncthreads();
  float wreg[8], breg[8];
#pragma unroll
  for (int f = 0; f < 8; ++f) { wreg[f] = Wg[f]; breg[f] = bg[f]; }
  for (int n = tid; n < 2000; n += 1024) {
    float a  = (float)Ai[n] * FXINV;
    float dd = (float)Di[n] * FXINV;
    unsigned int u[4];
#pragma unroll
    for (int p = 0; p < 4; ++p) {
      float v0 = tanh_fast(wreg[2 * p] * a + breg[2 * p] * dd);
      float v1 = tanh_fast(wreg[2 * p + 1] * a + breg[2 * p + 1] * dd);
      u[p] = (unsigned int)f2bf(v0) | ((unsigned int)f2bf(v1) << 16);
    }
    *(uint4*)&G[(size_t)bs * 16000 + n * 8] = make_uint4(u[0], u[1], u[2], u[3]);
  }
}

// ---------------- big MFMA GEMM: Zpart[p] = G @ W0^T (split-K) ----------------
__global__ __launch_bounds__(256) void gemm_bt(
    const unsigned short* __restrict__ A, const unsigned short* __restrict__ B,
    float* __restrict__ Cp) {
  __shared__ __align__(16) unsigned short As[128 * 32];
  __shared__ __align__(16) unsigned short Bs[128 * 32];
  const int K = 16000;
  int nt = blockIdx.x;
  int mt = blockIdx.y;
  int ks = blockIdx.z;
  int m0 = mt * 128, n0 = nt * 128;
  int tid = threadIdx.x;
  int lane = tid & 63;
  int w = tid >> 6;
  int wm = (w >> 1) * 64, wn = (w & 1) * 64;
  int fr = lane & 15;
  int kg = lane >> 4;

  f32x4 acc[4][4] = {};
  const unsigned short* Ag = A + (size_t)m0 * K + ks * 1600;
  const unsigned short* Bg = B + (size_t)n0 * K + ks * 1600;

  for (int kk = 0; kk < 1600; kk += 32) {
#pragma unroll
    for (int q = 0; q < 2; ++q) {
      int c = q * 256 + tid;
      int row = c >> 2;
      int ko = (c & 3) * 8;
      *(uint4*)&As[c * 8] = *(const uint4*)&Ag[(size_t)row * K + kk + ko];
      *(uint4*)&Bs[c * 8] = *(const uint4*)&Bg[(size_t)row * K + kk + ko];
    }
    __syncthreads();
    bf16x8 aF[4], bF[4];
#pragma unroll
    for (int i = 0; i < 4; ++i)
      aF[i] = *(const bf16x8*)&As[(wm + i * 16 + fr) * 32 + kg * 8];
#pragma unroll
    for (int i = 0; i < 4; ++i)
      bF[i] = *(const bf16x8*)&Bs[(wn + i * 16 + fr) * 32 + kg * 8];
#pragma unroll
    for (int i = 0; i < 4; ++i)
#pragma unroll
      for (int j = 0; j < 4; ++j)
        acc[i][j] = __builtin_amdgcn_mfma_f32_16x16x32_bf16(aF[i], bF[j], acc[i][j], 0, 0, 0);
    __syncthreads();
  }
  float* Co = Cp + (size_t)ks * 768 * 1024;
  int mr = (lane >> 4) * 4;
#pragma unroll
  for (int i = 0; i < 4; ++i)
#pragma unroll
    for (int j = 0; j < 4; ++j) {
      int n = n0 + wn + j * 16 + fr;
#pragma unroll
      for (int r = 0; r < 4; ++r) {
        int m = m0 + wm + i * 16 + mr + r;
        Co[(size_t)m * 1024 + n] = acc[i][j][r];
      }
    }
}

__global__ __launch_bounds__(256) void reduce_z0(
    const float* __restrict__ Cp, const float* __restrict__ bih,
    const float* __restrict__ bhh, float* __restrict__ Z0) {
  int id = blockIdx.x * 256 + threadIdx.x;   // 786,432 exact
  float s = bih[id & 1023] + bhh[id & 1023];
#pragma unroll
  for (int p = 0; p < 10; ++p) s += Cp[(size_t)p * 786432 + id];
  Z0[id] = s;
}

// ---------------- LSTM: one block per batch; weights 184 dw in VGPR + 72 dw in LDS ----------------
// Z: [32*24][1024] preactivations (biases included).
// WPK: [512][2][128] packed f16 k-pairs. Per thread/col: pairs 0..91 -> regs,
// 92..127 -> LDS (9 uint4 groups per col, [group][tid] layout for conflict-free b128).
// Hout (optional): f16 h history [32*24][256].
__global__ __launch_bounds__(512, 1) void lstm_fused(
    const float* __restrict__ Z, const unsigned int* __restrict__ WPK,
    unsigned short* __restrict__ Hout, float* __restrict__ lastOut) {
  __shared__ __align__(16) uint4 Wl4[18 * 512];          // 147,456 B
  __shared__ float g_lds[1024];                          // 4 KB
  __shared__ __align__(8) unsigned short h16[256];       // 512 B
  int b = blockIdx.x;
  int tid = threadIdx.x;
  int lane = tid & 63;

  // register-resident weights: pairs 0..91 per column (23 uint4 each)
  unsigned int wr0[92], wr1[92];
  const uint4* wp = (const uint4*)(WPK + (size_t)tid * 256);
#pragma unroll
  for (int q = 0; q < 23; ++q) {
    uint4 v = wp[q];
    wr0[q * 4] = v.x; wr0[q * 4 + 1] = v.y; wr0[q * 4 + 2] = v.z; wr0[q * 4 + 3] = v.w;
  }
#pragma unroll
  for (int q = 0; q < 23; ++q) {
    uint4 v = wp[32 + q];
    wr1[q * 4] = v.x; wr1[q * 4 + 1] = v.y; wr1[q * 4 + 2] = v.z; wr1[q * 4 + 3] = v.w;
  }
  // LDS-resident weights: col0 pairs 92..127 -> groups 0..8; col1 -> groups 9..17
#pragma unroll
  for (int g = 0; g < 9; ++g)
    Wl4[g * 512 + tid] = wp[23 + g];
#pragma unroll
  for (int g = 0; g < 9; ++g)
    Wl4[(9 + g) * 512 + tid] = wp[55 + g];
  if (tid < 128) ((unsigned int*)h16)[tid] = 0;
  __syncthreads();

  float cst = 0.f;
  const size_t b24 = (size_t)b * 24;
  const float* Zb = Z + b24 * 1024 + tid;

#pragma unroll 1
  for (int t = 0; t < 24; ++t) {
    uint2 hv = *(const uint2*)&((const unsigned int*)h16)[lane * 2];
    float z0 = Zb[t * 1024];
    float z1 = Zb[t * 1024 + 512];
    float a0a = 0.f, a0b = 0.f, a1a = 0.f, a1b = 0.f;
    // register phase: u = 0..91
#pragma unroll
    for (int u = 0; u < 92; ++u) {
      unsigned int hu = (unsigned int)__builtin_amdgcn_readlane(
          (int)((u & 1) ? hv.y : hv.x), u >> 1);
      if (u & 1) { a0b = fdot2u(hu, wr0[u], a0b); a1b = fdot2u(hu, wr1[u], a1b); }
      else       { a0a = fdot2u(hu, wr0[u], a0a); a1a = fdot2u(hu, wr1[u], a1a); }
    }
    // LDS phase: u = 92..127 (9 groups of 4; same hu reused for both columns)
#pragma unroll
    for (int g = 0; g < 9; ++g) {
      uint4 wa = Wl4[g * 512 + tid];
      uint4 wb = Wl4[(9 + g) * 512 + tid];
#pragma unroll
      for (int r = 0; r < 4; ++r) {
        const int u = 92 + g * 4 + r;
        unsigned int hu = (unsigned int)__builtin_amdgcn_readlane(
            (int)((u & 1) ? hv.y : hv.x), u >> 1);
        unsigned int w0r = (r == 0) ? wa.x : (r == 1) ? wa.y : (r == 2) ? wa.z : wa.w;
        unsigned int w1r = (r == 0) ? wb.x : (r == 1) ? wb.y : (r == 2) ? wb.z : wb.w;
        if (u & 1) { a0b = fdot2u(hu, w0r, a0b); a1b = fdot2u(hu, w1r, a1b); }
        else       { a0a = fdot2u(hu, w0r, a0a); a1a = fdot2u(hu, w1r, a1a); }
      }
    }
    g_lds[tid] = z0 + a0a + a0b;
    g_lds[tid + 512] = z1 + a1a + a1b;
    __syncthreads();
    if (tid < 256) {
      float ig = sigmf(g_lds[tid]);
      float fg = sigmf(g_lds[tid + 256]);
      float gg = tanh_fast(g_lds[tid + 512]);
      float og = sigmf(g_lds[tid + 768]);
      cst = fg * cst + ig * gg;
      float h = og * tanh_fast(cst);
      unsigned short hh = __builtin_bit_cast(unsigned short, (_Float16)h);
      h16[tid] = hh;
      if (Hout) Hout[(b24 + t) * 256 + tid] = hh;
      if (lastOut && t == 23) lastOut[b * 256 + tid] = tanh_fast(h);
    }
    __syncthreads();
  }
}

// ---------------- Z1 = H1f16 @ Wih1f16^T + biases (MFMA) ----------------
__global__ __launch_bounds__(256) void gemm_z1_mfma(
    const unsigned short* __restrict__ A, const unsigned short* __restrict__ B,
    const float* __restrict__ bih, const float* __restrict__ bhh,
    float* __restrict__ Z1) {
  __shared__ __align__(16) unsigned short As[128 * 32];
  __shared__ __align__(16) unsigned short Bs[128 * 32];
  const int K = 256;
  int nt = blockIdx.x;   // 0..7
  int mt = blockIdx.y;   // 0..5
  int m0 = mt * 128, n0 = nt * 128;
  int tid = threadIdx.x;
  int lane = tid & 63;
  int w = tid >> 6;
  int wm = (w >> 1) * 64, wn = (w & 1) * 64;
  int fr = lane & 15;
  int kg = lane >> 4;

  f32x4 acc[4][4] = {};
  const unsigned short* Ag = A + (size_t)m0 * K;
  const unsigned short* Bg = B + (size_t)n0 * K;

  for (int kk = 0; kk < 256; kk += 32) {
#pragma unroll
    for (int q = 0; q < 2; ++q) {
      int c = q * 256 + tid;
      int row = c >> 2;
      int ko = (c & 3) * 8;
      *(uint4*)&As[c * 8] = *(const uint4*)&Ag[(size_t)row * K + kk + ko];
      *(uint4*)&Bs[c * 8] = *(const uint4*)&Bg[(size_t)row * K + kk + ko];
    }
    __syncthreads();
    f16x8 aF[4], bF[4];
#pragma unroll
    for (int i = 0; i < 4; ++i)
      aF[i] = *(const f16x8*)&As[(wm + i * 16 + fr) * 32 + kg * 8];
#pragma unroll
    for (int i = 0; i < 4; ++i)
      bF[i] = *(const f16x8*)&Bs[(wn + i * 16 + fr) * 32 + kg * 8];
#pragma unroll
    for (int i = 0; i < 4; ++i)
#pragma unroll
      for (int j = 0; j < 4; ++j)
        acc[i][j] = __builtin_amdgcn_mfma_f32_16x16x32_f16(aF[i], bF[j], acc[i][j], 0, 0, 0);
    __syncthreads();
  }
  int mr = (lane >> 4) * 4;
#pragma unroll
  for (int j = 0; j < 4; ++j) {
    int n = n0 + wn + j * 16 + fr;
    float bias = bih[n] + bhh[n];
#pragma unroll
    for (int i = 0; i < 4; ++i) {
#pragma unroll
      for (int r = 0; r < 4; ++r) {
        int m = m0 + wm + i * 16 + mr + r;
        Z1[(size_t)m * 1024 + n] = acc[i][j][r] + bias;
      }
    }
  }
}

// ---------------- fc: out = last @ fc_W^T + fc_b ----------------
__global__ __launch_bounds__(256) void fc_kernel(
    const float* __restrict__ last, const float* __restrict__ fcW,
    const float* __restrict__ fcb, float* __restrict__ out) {
  __shared__ float ls[8][256];
  int tid = threadIdx.x;
  int o = blockIdx.x * 256 + tid;
  int b0 = blockIdx.y * 8;
  for (int i = tid; i < 2048; i += 256)
    ls[i >> 8][i & 255] = last[(b0 + (i >> 8)) * 256 + (i & 255)];
  __syncthreads();
  if (o < 8000) {
    float acc[8] = {};
    for (int k = 0; k < 256; k += 4) {
      float4 wv = *(const float4*)&fcW[(size_t)o * 256 + k];
#pragma unroll
      for (int b = 0; b < 8; ++b)
        acc[b] += wv.x * ls[b][k] + wv.y * ls[b][k + 1] + wv.z * ls[b][k + 2] + wv.w * ls[b][k + 3];
    }
    float bias = fcb[o];
#pragma unroll
    for (int b = 0; b < 8; ++b) out[(size_t)(b0 + b) * 8000 + o] = acc[b] + bias;
  }
}

// ---------------- launch ----------------
extern "C" void kernel_launch(void* const* d_in, const int* in_sizes, int n_in,
                              void* d_out, int out_size, void* d_ws, size_t ws_size,
                              hipStream_t stream) {
  const float* x    = (const float*)d_in[0];
  const int*   ei   = (const int*)d_in[1];
  const float* ed   = (const float*)d_in[2];
  const float* Wg   = (const float*)d_in[3];
  const float* bg   = (const float*)d_in[4];
  const float* Wih0 = (const float*)d_in[5];
  const float* Whh0 = (const float*)d_in[6];
  const float* bih0 = (const float*)d_in[7];
  const float* bhh0 = (const float*)d_in[8];
  const float* Wih1 = (const float*)d_in[9];
  const float* Whh1 = (const float*)d_in[10];
  const float* bih1 = (const float*)d_in[11];
  const float* bhh1 = (const float*)d_in[12];
  const float* fcW  = (const float*)d_in[13];
  const float* fcb  = (const float*)d_in[14];
  float* out = (float*)d_out;

  char* ws = (char*)d_ws;
  unsigned short* Gbf  = (unsigned short*)(ws);              // 24,576,000
  unsigned short* W0bf = (unsigned short*)(ws + 24576000);   // 32,768,000
  float* Zpart = (float*)(ws + 57344000);                    // 31,457,280
  float* Z0    = (float*)(ws + 88801280);                    //  3,145,728
  unsigned int* WPK0 = (unsigned int*)(ws + 91947008);       //    524,288
  unsigned int* WPK1 = (unsigned int*)(ws + 92471296);       //    524,288
  unsigned short* W1h = (unsigned short*)(ws + 92995584);    //    524,288 (f16 Wih1)
  unsigned short* H1  = (unsigned short*)(ws + 94044160);    //    393,216 (f16 H1)
  float* Z1    = (float*)(ws + 94830592);                    //  3,145,728
  float* lastb = (float*)(ws + 97976320);                    //     32,768  (end ~98 MB)

  conv_bf16<<<16000, 256, 0, stream>>>(Wih0, W0bf);
  pack_whh_f16<<<512, 256, 0, stream>>>(Whh0, WPK0);
  pack_whh_f16<<<512, 256, 0, stream>>>(Whh1, WPK1);
  conv_f16<<<1024, 256, 0, stream>>>(Wih1, (unsigned short*)W1h);
  gcn_kernel<<<768, 1024, 0, stream>>>(x, ei, ed, Wg, bg, Gbf);
  gemm_bt<<<dim3(8, 6, 10), 256, 0, stream>>>(Gbf, W0bf, Zpart);
  reduce_z0<<<3072, 256, 0, stream>>>(Zpart, bih0, bhh0, Z0);
  lstm_fused<<<32, 512, 0, stream>>>(Z0, WPK0, H1, nullptr);
  gemm_z1_mfma<<<dim3(8, 6), 256, 0, stream>>>(H1, W1h, bih1, bhh1, Z1);
  lstm_fused<<<32, 512, 0, stream>>>(Z1, WPK1, nullptr, lastb);
  fc_kernel<<<dim3(32, 4), 256, 0, stream>>>(lastb, fcW, fcb, out);
}